// Round 1
// baseline (545.535 us; speedup 1.0000x reference)
//
#include <hip/hip_runtime.h>
#include <hip/hip_bf16.h>
#include <stdint.h>

#define S_LEN 2048
#define DH    64
#define NBH   64          // B*H = 4*16
#define QR    128         // q-rows per workgroup
#define KTI   64          // k-cols per tile
#define NT    (S_LEN / KTI)   // 32 tiles
#define NTHR  512
#define SCALE 0.125f      // 1/sqrt(64)

using f32x4   = __attribute__((ext_vector_type(4))) float;
using short8v = __attribute__((ext_vector_type(8))) short;

__device__ __forceinline__ short f2bf(float f) {
    union { float f; uint32_t u; } v; v.f = f;
    uint32_t u = v.u;
    uint32_t r = (u + 0x7FFFu + ((u >> 16) & 1u)) >> 16;  // RNE
    return (short)r;
}

// Pack mask into per-lane bitmasks: for lane c of a 16-lane group handling
// q-rows [4*q4 .. 4*q4+3] and k-tile t, bit (r*4+n) = mask[q4*4+r][t*64+n*16+c]
__global__ void pack_mask_kernel(const int* __restrict__ mask, uint32_t* __restrict__ pmL) {
    int tid = blockIdx.x * 256 + threadIdx.x;       // 0 .. 512*32*16-1
    int c  = tid & 15;
    int t  = (tid >> 4) & (NT - 1);
    int q4 = tid >> 9;
    uint32_t bits = 0;
    #pragma unroll
    for (int r = 0; r < 4; ++r)
        #pragma unroll
        for (int n = 0; n < 4; ++n) {
            int q = q4 * 4 + r;
            int k = t * KTI + n * 16 + c;
            if (mask[q * S_LEN + k]) bits |= 1u << (r * 4 + n);
        }
    pmL[tid] = bits;
}

__global__ __launch_bounds__(NTHR, 4)
void attn_kernel(const float* __restrict__ Q, const float* __restrict__ K,
                 const float* __restrict__ V, const uint32_t* __restrict__ pmask,
                 float* __restrict__ outC, float* __restrict__ outA)
{
    __shared__ short Qs[QR][72];      // bf16 bits, padded stride
    __shared__ short Ks[KTI][72];
    __shared__ short VT[DH][72];      // V transposed: VT[d][k]
    __shared__ short Ps[8][16][72];   // per-wave P tile (A-frag layout)

    const int bh  = blockIdx.x;
    const int q0  = blockIdx.y * QR;
    const int tid = threadIdx.x;
    const int w   = tid >> 6;
    const int l   = tid & 63;
    const int l16 = l & 15;
    const int g   = l >> 4;

    const float* Qb = Q + ((size_t)bh * S_LEN + q0) * DH;
    const float* Kb = K + (size_t)bh * S_LEN * DH;
    const float* Vb = V + (size_t)bh * S_LEN * DH;
    float* Cb = outC + ((size_t)bh * S_LEN + q0) * DH;
    float* Ab = outA + (size_t)bh * S_LEN * S_LEN + (size_t)q0 * S_LEN;

    // ---- stage Q tile (128x64 fp32 -> bf16) ----
    #pragma unroll
    for (int i = 0; i < 4; ++i) {
        int v   = tid + i * NTHR;      // 0..2047 (float4 index)
        int row = v >> 4;
        int c4  = (v & 15) << 2;
        float4 q4 = *reinterpret_cast<const float4*>(Qb + row * DH + c4);
        short* dst = &Qs[row][c4];
        dst[0] = f2bf(q4.x); dst[1] = f2bf(q4.y); dst[2] = f2bf(q4.z); dst[3] = f2bf(q4.w);
    }
    __syncthreads();

    // per-wave Q A-fragments (rows w*16 + l16), two K=32 steps
    short8v aq0 = *reinterpret_cast<const short8v*>(&Qs[w * 16 + l16][g * 8]);
    short8v aq1 = *reinterpret_cast<const short8v*>(&Qs[w * 16 + l16][32 + g * 8]);

    const int q4base = (q0 >> 2) + (w << 2) + g;   // global q-row/4 for this lane group

    float m_r[4], l_r[4];
    #pragma unroll
    for (int r = 0; r < 4; ++r) { m_r[r] = -1e30f; l_r[r] = 0.0f; }

    // ================= phase 1: softmax stats (m, l) =================
    for (int t = 0; t < NT; ++t) {
        __syncthreads();
        #pragma unroll
        for (int i = 0; i < 2; ++i) {
            int v   = tid + i * NTHR;   // 0..1023
            int row = v >> 4;
            int c4  = (v & 15) << 2;
            float4 k4 = *reinterpret_cast<const float4*>(Kb + (size_t)(t * KTI + row) * DH + c4);
            short* dst = &Ks[row][c4];
            dst[0] = f2bf(k4.x); dst[1] = f2bf(k4.y); dst[2] = f2bf(k4.z); dst[3] = f2bf(k4.w);
        }
        __syncthreads();

        uint32_t mb = pmask[(size_t)q4base * (NT * 16) + (t << 4) + l16];

        f32x4 acc[4];
        #pragma unroll
        for (int n = 0; n < 4; ++n) {
            short8v b0 = *reinterpret_cast<const short8v*>(&Ks[n * 16 + l16][g * 8]);
            short8v b1 = *reinterpret_cast<const short8v*>(&Ks[n * 16 + l16][32 + g * 8]);
            f32x4 a = {0.f, 0.f, 0.f, 0.f};
            a = __builtin_amdgcn_mfma_f32_16x16x32_bf16(aq0, b0, a, 0, 0, 0);
            a = __builtin_amdgcn_mfma_f32_16x16x32_bf16(aq1, b1, a, 0, 0, 0);
            acc[n] = a;
        }

        float pmax[4] = {-1e30f, -1e30f, -1e30f, -1e30f};
        #pragma unroll
        for (int n = 0; n < 4; ++n)
            #pragma unroll
            for (int r = 0; r < 4; ++r) {
                float s = acc[n][r] * SCALE;
                bool ok = (mb >> (r * 4 + n)) & 1u;
                pmax[r] = fmaxf(pmax[r], ok ? s : -1e30f);
            }

        #pragma unroll
        for (int r = 0; r < 4; ++r) {
            float v = pmax[r];
            v = fmaxf(v, __shfl_xor(v, 1));
            v = fmaxf(v, __shfl_xor(v, 2));
            v = fmaxf(v, __shfl_xor(v, 4));
            v = fmaxf(v, __shfl_xor(v, 8));
            float mnew = fmaxf(m_r[r], v);
            float ls = 0.f;
            #pragma unroll
            for (int n = 0; n < 4; ++n) {
                float s = acc[n][r] * SCALE;
                bool ok = (mb >> (r * 4 + n)) & 1u;
                ls += ok ? __expf(s - mnew) : 0.f;
            }
            ls += __shfl_xor(ls, 1);
            ls += __shfl_xor(ls, 2);
            ls += __shfl_xor(ls, 4);
            ls += __shfl_xor(ls, 8);
            l_r[r] = l_r[r] * __expf(m_r[r] - mnew) + ls;
            m_r[r] = mnew;
        }
    }

    float li[4];
    #pragma unroll
    for (int r = 0; r < 4; ++r) li[r] = 1.0f / l_r[r];

    f32x4 acco[4];
    #pragma unroll
    for (int n = 0; n < 4; ++n) acco[n] = (f32x4){0.f, 0.f, 0.f, 0.f};

    // ================= phase 2: attn write + PV =================
    for (int t = 0; t < NT; ++t) {
        __syncthreads();
        #pragma unroll
        for (int i = 0; i < 2; ++i) {
            int v   = tid + i * NTHR;
            int row = v >> 4;
            int c4  = (v & 15) << 2;
            float4 k4 = *reinterpret_cast<const float4*>(Kb + (size_t)(t * KTI + row) * DH + c4);
            short* dst = &Ks[row][c4];
            dst[0] = f2bf(k4.x); dst[1] = f2bf(k4.y); dst[2] = f2bf(k4.z); dst[3] = f2bf(k4.w);
            float4 v4 = *reinterpret_cast<const float4*>(Vb + (size_t)(t * KTI + row) * DH + c4);
            VT[c4 + 0][row] = f2bf(v4.x);
            VT[c4 + 1][row] = f2bf(v4.y);
            VT[c4 + 2][row] = f2bf(v4.z);
            VT[c4 + 3][row] = f2bf(v4.w);
        }
        __syncthreads();

        uint32_t mb = pmask[(size_t)q4base * (NT * 16) + (t << 4) + l16];

        f32x4 acc[4];
        #pragma unroll
        for (int n = 0; n < 4; ++n) {
            short8v b0 = *reinterpret_cast<const short8v*>(&Ks[n * 16 + l16][g * 8]);
            short8v b1 = *reinterpret_cast<const short8v*>(&Ks[n * 16 + l16][32 + g * 8]);
            f32x4 a = {0.f, 0.f, 0.f, 0.f};
            a = __builtin_amdgcn_mfma_f32_16x16x32_bf16(aq0, b0, a, 0, 0, 0);
            a = __builtin_amdgcn_mfma_f32_16x16x32_bf16(aq1, b1, a, 0, 0, 0);
            acc[n] = a;
        }

        // normalized probabilities: write attn (fp32) + stage into Ps (bf16)
        #pragma unroll
        for (int n = 0; n < 4; ++n)
            #pragma unroll
            for (int r = 0; r < 4; ++r) {
                float s = acc[n][r] * SCALE;
                bool ok = (mb >> (r * 4 + n)) & 1u;
                float p = ok ? __expf(s - m_r[r]) * li[r] : 0.0f;
                Ab[(size_t)(w * 16 + 4 * g + r) * S_LEN + t * KTI + n * 16 + l16] = p;
                Ps[w][4 * g + r][n * 16 + l16] = f2bf(p);
            }

        // PV: O += P(16xKTI) * V(KTIxDH); A from Ps, B from VT (both b128 reads)
        short8v ap0 = *reinterpret_cast<const short8v*>(&Ps[w][l16][g * 8]);
        short8v ap1 = *reinterpret_cast<const short8v*>(&Ps[w][l16][32 + g * 8]);
        #pragma unroll
        for (int n = 0; n < 4; ++n) {
            short8v b0 = *reinterpret_cast<const short8v*>(&VT[n * 16 + l16][g * 8]);
            short8v b1 = *reinterpret_cast<const short8v*>(&VT[n * 16 + l16][32 + g * 8]);
            acco[n] = __builtin_amdgcn_mfma_f32_16x16x32_bf16(ap0, b0, acco[n], 0, 0, 0);
            acco[n] = __builtin_amdgcn_mfma_f32_16x16x32_bf16(ap1, b1, acco[n], 0, 0, 0);
        }
    }

    // ---- write context ----
    #pragma unroll
    for (int n = 0; n < 4; ++n)
        #pragma unroll
        for (int r = 0; r < 4; ++r)
            Cb[(w * 16 + 4 * g + r) * DH + n * 16 + l16] = acco[n][r];
}

extern "C" void kernel_launch(void* const* d_in, const int* in_sizes, int n_in,
                              void* d_out, int out_size, void* d_ws, size_t ws_size,
                              hipStream_t stream)
{
    const float* Q    = (const float*)d_in[0];
    const float* K    = (const float*)d_in[1];
    const float* V    = (const float*)d_in[2];
    const int*   mask = (const int*)d_in[3];

    float* outC = (float*)d_out;
    float* outA = (float*)d_out + (size_t)NBH * S_LEN * DH;   // context first, then attn
    uint32_t* pmL = (uint32_t*)d_ws;                          // 1 MB packed mask

    pack_mask_kernel<<<dim3((S_LEN / 4) * NT * 16 / 256), 256, 0, stream>>>(mask, pmL);
    attn_kernel<<<dim3(NBH, S_LEN / QR), NTHR, 0, stream>>>(Q, K, V, pmL, outC, outA);
}

// Round 2
// 533.648 us; speedup vs baseline: 1.0223x; 1.0223x over previous
//
#include <hip/hip_runtime.h>
#include <hip/hip_bf16.h>
#include <stdint.h>

#define S_LEN 2048
#define DH    64
#define NBH   64          // B*H = 4*16
#define QR    128         // q-rows per workgroup
#define KTI   64          // k-cols per tile
#define NT    (S_LEN / KTI)   // 32 tiles
#define NTHR  512
#define SCALE2 (0.125f * 1.44269504f)   // (1/sqrt(64)) * log2(e)
#define EXPB2  23.0f                    // fixed softmax bias (base-2)

using f32x4   = __attribute__((ext_vector_type(4))) float;
using short8v = __attribute__((ext_vector_type(8))) short;

__device__ __forceinline__ short f2bf(float f) {
    union { float f; uint32_t u; } v; v.f = f;
    uint32_t u = v.u;
    return (short)((u + 0x7FFFu + ((u >> 16) & 1u)) >> 16);  // RNE
}

// Pack mask into per-lane bitmasks: for lane c of a 16-lane group handling
// q-rows [4*q4 .. 4*q4+3] and k-tile t, bit (r*4+n) = mask[q4*4+r][t*64+n*16+c]
__global__ void pack_mask_kernel(const int* __restrict__ mask, uint32_t* __restrict__ pmL) {
    int tid = blockIdx.x * 256 + threadIdx.x;       // 0 .. 512*32*16-1
    int c  = tid & 15;
    int t  = (tid >> 4) & (NT - 1);
    int q4 = tid >> 9;
    uint32_t bits = 0;
    #pragma unroll
    for (int r = 0; r < 4; ++r)
        #pragma unroll
        for (int n = 0; n < 4; ++n) {
            int q = q4 * 4 + r;
            int k = t * KTI + n * 16 + c;
            if (mask[q * S_LEN + k]) bits |= 1u << (r * 4 + n);
        }
    pmL[tid] = bits;
}

__global__ __launch_bounds__(NTHR, 4)
void attn_kernel(const float* __restrict__ Q, const float* __restrict__ K,
                 const float* __restrict__ V, const uint32_t* __restrict__ pmask,
                 float* __restrict__ outC, float* __restrict__ outA)
{
    __shared__ short Qs[QR][72];         // bf16 bits, padded stride
    __shared__ short Ks[2][KTI][72];     // double-buffered K tile
    __shared__ short VT[2][DH][72];      // double-buffered V^T tile
    __shared__ short Ps[8][16][72];      // per-wave P tile (A-frag layout)

    const int bh  = blockIdx.x;
    const int q0  = blockIdx.y * QR;
    const int tid = threadIdx.x;
    const int w   = tid >> 6;
    const int l   = tid & 63;
    const int l16 = l & 15;
    const int g   = l >> 4;
    const int sr  = tid >> 4;            // staging row base (0..31)
    const int sc  = (tid & 15) << 2;     // staging col (0,4,...,60)

    const float* Qb = Q + ((size_t)bh * S_LEN + q0) * DH;
    const float* Kb = K + (size_t)bh * S_LEN * DH;
    const float* Vb = V + (size_t)bh * S_LEN * DH;
    float* Cb = outC + ((size_t)bh * S_LEN + q0) * DH;
    float* Ab = outA + (size_t)bh * S_LEN * S_LEN + (size_t)q0 * S_LEN;

    // ---- stage Q tile (128x64 fp32 -> bf16) ----
    #pragma unroll
    for (int i = 0; i < 4; ++i) {
        int v   = tid + i * NTHR;        // 0..2047 (float4 index)
        int row = v >> 4;
        int c4  = (v & 15) << 2;
        float4 q4 = *reinterpret_cast<const float4*>(Qb + row * DH + c4);
        short* dst = &Qs[row][c4];
        dst[0] = f2bf(q4.x); dst[1] = f2bf(q4.y); dst[2] = f2bf(q4.z); dst[3] = f2bf(q4.w);
    }
    __syncthreads();

    // per-wave Q A-fragments (rows w*16 + l16), two K=32 steps
    short8v aq0 = *reinterpret_cast<const short8v*>(&Qs[w * 16 + l16][g * 8]);
    short8v aq1 = *reinterpret_cast<const short8v*>(&Qs[w * 16 + l16][32 + g * 8]);

    const uint32_t* pmb = pmask + (size_t)((q0 >> 2) + (w << 2) + g) * (NT * 16) + l16;

    // ================= phase 1: softmax denominators (fixed-bias, no max) =================
    float ls[4] = {0.f, 0.f, 0.f, 0.f};
    {
        float4 k0 = *reinterpret_cast<const float4*>(Kb + (size_t)(sr) * DH + sc);
        float4 k1 = *reinterpret_cast<const float4*>(Kb + (size_t)(sr + 32) * DH + sc);
        short* d0 = &Ks[0][sr][sc];
        d0[0] = f2bf(k0.x); d0[1] = f2bf(k0.y); d0[2] = f2bf(k0.z); d0[3] = f2bf(k0.w);
        short* d1 = &Ks[0][sr + 32][sc];
        d1[0] = f2bf(k1.x); d1[1] = f2bf(k1.y); d1[2] = f2bf(k1.z); d1[3] = f2bf(k1.w);
    }
    __syncthreads();

    for (int t = 0; t < NT; ++t) {
        const int  cur  = t & 1;
        const bool more = (t + 1 < NT);
        float4 nk0, nk1;
        if (more) {
            nk0 = *reinterpret_cast<const float4*>(Kb + (size_t)((t + 1) * KTI + sr) * DH + sc);
            nk1 = *reinterpret_cast<const float4*>(Kb + (size_t)((t + 1) * KTI + sr + 32) * DH + sc);
        }
        uint32_t mb = pmb[t << 4];

        f32x4 acc[4];
        #pragma unroll
        for (int n = 0; n < 4; ++n) {
            short8v b0 = *reinterpret_cast<const short8v*>(&Ks[cur][n * 16 + l16][g * 8]);
            short8v b1 = *reinterpret_cast<const short8v*>(&Ks[cur][n * 16 + l16][32 + g * 8]);
            f32x4 a = {0.f, 0.f, 0.f, 0.f};
            a = __builtin_amdgcn_mfma_f32_16x16x32_bf16(aq0, b0, a, 0, 0, 0);
            a = __builtin_amdgcn_mfma_f32_16x16x32_bf16(aq1, b1, a, 0, 0, 0);
            acc[n] = a;
        }

        #pragma unroll
        for (int n = 0; n < 4; ++n)
            #pragma unroll
            for (int r = 0; r < 4; ++r) {
                float e = __builtin_amdgcn_exp2f(acc[n][r] * SCALE2 - EXPB2);
                ls[r] += ((mb >> (r * 4 + n)) & 1u) ? e : 0.f;
            }

        if (more) {
            short* d0 = &Ks[cur ^ 1][sr][sc];
            d0[0] = f2bf(nk0.x); d0[1] = f2bf(nk0.y); d0[2] = f2bf(nk0.z); d0[3] = f2bf(nk0.w);
            short* d1 = &Ks[cur ^ 1][sr + 32][sc];
            d1[0] = f2bf(nk1.x); d1[1] = f2bf(nk1.y); d1[2] = f2bf(nk1.z); d1[3] = f2bf(nk1.w);
        }
        __syncthreads();
    }

    // reduce row sums across the 16-lane group, once
    float li[4];
    #pragma unroll
    for (int r = 0; r < 4; ++r) {
        float v = ls[r];
        v += __shfl_xor(v, 1);
        v += __shfl_xor(v, 2);
        v += __shfl_xor(v, 4);
        v += __shfl_xor(v, 8);
        li[r] = 1.0f / v;
    }

    f32x4 acco[4];
    #pragma unroll
    for (int n = 0; n < 4; ++n) acco[n] = (f32x4){0.f, 0.f, 0.f, 0.f};

    float* Abl = Ab + (size_t)(w * 16 + 4 * g) * S_LEN + l16;

    // ================= phase 2: attn write + PV =================
    {
        float4 k0 = *reinterpret_cast<const float4*>(Kb + (size_t)(sr) * DH + sc);
        float4 k1 = *reinterpret_cast<const float4*>(Kb + (size_t)(sr + 32) * DH + sc);
        float4 v0 = *reinterpret_cast<const float4*>(Vb + (size_t)(sr) * DH + sc);
        float4 v1 = *reinterpret_cast<const float4*>(Vb + (size_t)(sr + 32) * DH + sc);
        short* d0 = &Ks[0][sr][sc];
        d0[0] = f2bf(k0.x); d0[1] = f2bf(k0.y); d0[2] = f2bf(k0.z); d0[3] = f2bf(k0.w);
        short* d1 = &Ks[0][sr + 32][sc];
        d1[0] = f2bf(k1.x); d1[1] = f2bf(k1.y); d1[2] = f2bf(k1.z); d1[3] = f2bf(k1.w);
        VT[0][sc + 0][sr] = f2bf(v0.x); VT[0][sc + 1][sr] = f2bf(v0.y);
        VT[0][sc + 2][sr] = f2bf(v0.z); VT[0][sc + 3][sr] = f2bf(v0.w);
        VT[0][sc + 0][sr + 32] = f2bf(v1.x); VT[0][sc + 1][sr + 32] = f2bf(v1.y);
        VT[0][sc + 2][sr + 32] = f2bf(v1.z); VT[0][sc + 3][sr + 32] = f2bf(v1.w);
    }
    __syncthreads();

    for (int t = 0; t < NT; ++t) {
        const int  cur  = t & 1;
        const bool more = (t + 1 < NT);
        float4 nk0, nk1, nv0, nv1;
        if (more) {
            nk0 = *reinterpret_cast<const float4*>(Kb + (size_t)((t + 1) * KTI + sr) * DH + sc);
            nk1 = *reinterpret_cast<const float4*>(Kb + (size_t)((t + 1) * KTI + sr + 32) * DH + sc);
            nv0 = *reinterpret_cast<const float4*>(Vb + (size_t)((t + 1) * KTI + sr) * DH + sc);
            nv1 = *reinterpret_cast<const float4*>(Vb + (size_t)((t + 1) * KTI + sr + 32) * DH + sc);
        }
        uint32_t mb = pmb[t << 4];

        f32x4 acc[4];
        #pragma unroll
        for (int n = 0; n < 4; ++n) {
            short8v b0 = *reinterpret_cast<const short8v*>(&Ks[cur][n * 16 + l16][g * 8]);
            short8v b1 = *reinterpret_cast<const short8v*>(&Ks[cur][n * 16 + l16][32 + g * 8]);
            f32x4 a = {0.f, 0.f, 0.f, 0.f};
            a = __builtin_amdgcn_mfma_f32_16x16x32_bf16(aq0, b0, a, 0, 0, 0);
            a = __builtin_amdgcn_mfma_f32_16x16x32_bf16(aq1, b1, a, 0, 0, 0);
            acc[n] = a;
        }

        // normalized probabilities: write attn (fp32) + stage into Ps (bf16)
        #pragma unroll
        for (int n = 0; n < 4; ++n)
            #pragma unroll
            for (int r = 0; r < 4; ++r) {
                float e = __builtin_amdgcn_exp2f(acc[n][r] * SCALE2 - EXPB2) * li[r];
                float p = ((mb >> (r * 4 + n)) & 1u) ? e : 0.0f;
                Abl[(size_t)r * S_LEN + t * KTI + n * 16] = p;
                Ps[w][4 * g + r][n * 16 + l16] = f2bf(p);
            }

        // PV: O += P(16xKTI) * V(KTIxDH); A from Ps, B from VT (both b128 reads)
        short8v ap0 = *reinterpret_cast<const short8v*>(&Ps[w][l16][g * 8]);
        short8v ap1 = *reinterpret_cast<const short8v*>(&Ps[w][l16][32 + g * 8]);
        #pragma unroll
        for (int n = 0; n < 4; ++n) {
            short8v b0 = *reinterpret_cast<const short8v*>(&VT[cur][n * 16 + l16][g * 8]);
            short8v b1 = *reinterpret_cast<const short8v*>(&VT[cur][n * 16 + l16][32 + g * 8]);
            acco[n] = __builtin_amdgcn_mfma_f32_16x16x32_bf16(ap0, b0, acco[n], 0, 0, 0);
            acco[n] = __builtin_amdgcn_mfma_f32_16x16x32_bf16(ap1, b1, acco[n], 0, 0, 0);
        }

        if (more) {
            const int nb = cur ^ 1;
            short* d0 = &Ks[nb][sr][sc];
            d0[0] = f2bf(nk0.x); d0[1] = f2bf(nk0.y); d0[2] = f2bf(nk0.z); d0[3] = f2bf(nk0.w);
            short* d1 = &Ks[nb][sr + 32][sc];
            d1[0] = f2bf(nk1.x); d1[1] = f2bf(nk1.y); d1[2] = f2bf(nk1.z); d1[3] = f2bf(nk1.w);
            VT[nb][sc + 0][sr] = f2bf(nv0.x); VT[nb][sc + 1][sr] = f2bf(nv0.y);
            VT[nb][sc + 2][sr] = f2bf(nv0.z); VT[nb][sc + 3][sr] = f2bf(nv0.w);
            VT[nb][sc + 0][sr + 32] = f2bf(nv1.x); VT[nb][sc + 1][sr + 32] = f2bf(nv1.y);
            VT[nb][sc + 2][sr + 32] = f2bf(nv1.z); VT[nb][sc + 3][sr + 32] = f2bf(nv1.w);
        }
        __syncthreads();
    }

    // ---- write context ----
    #pragma unroll
    for (int n = 0; n < 4; ++n)
        #pragma unroll
        for (int r = 0; r < 4; ++r)
            Cb[(w * 16 + 4 * g + r) * DH + n * 16 + l16] = acco[n][r];
}

extern "C" void kernel_launch(void* const* d_in, const int* in_sizes, int n_in,
                              void* d_out, int out_size, void* d_ws, size_t ws_size,
                              hipStream_t stream)
{
    const float* Q    = (const float*)d_in[0];
    const float* K    = (const float*)d_in[1];
    const float* V    = (const float*)d_in[2];
    const int*   mask = (const int*)d_in[3];

    float* outC = (float*)d_out;
    float* outA = (float*)d_out + (size_t)NBH * S_LEN * DH;   // context first, then attn
    uint32_t* pmL = (uint32_t*)d_ws;                          // 1 MB packed mask

    pack_mask_kernel<<<dim3((S_LEN / 4) * NT * 16 / 256), 256, 0, stream>>>(mask, pmL);
    attn_kernel<<<dim3(NBH, S_LEN / QR), NTHR, 0, stream>>>(Q, K, V, pmL, outC, outA);
}

// Round 4
// 372.763 us; speedup vs baseline: 1.4635x; 1.4316x over previous
//
#include <hip/hip_runtime.h>
#include <hip/hip_bf16.h>
#include <stdint.h>

#define S_LEN 2048
#define DH    64
#define NBH   64          // B*H = 4*16
#define QR    128         // q-rows per workgroup
#define KTI   64          // k-cols per tile
#define NT    (S_LEN / KTI)   // 32 tiles
#define NTHR  512
#define SCALE2 (0.125f * 1.44269504f)   // (1/sqrt(64)) * log2(e)
#define EXPB2  23.0f                    // fixed softmax bias (base-2)

using f32x4   = __attribute__((ext_vector_type(4))) float;
using short8v = __attribute__((ext_vector_type(8))) short;
using short4v = __attribute__((ext_vector_type(4))) short;

__device__ __forceinline__ short f2bf(float f) {
    union { float f; uint32_t u; } v; v.f = f;
    uint32_t u = v.u;
    return (short)((u + 0x7FFFu + ((u >> 16) & 1u)) >> 16);  // RNE
}

// ---------- prep kernels ----------

// Pack mask into per-lane bitmasks (bit (r*4+n) = mask[q4*4+r][t*64+n*16+c])
__global__ void pack_mask_kernel(const int* __restrict__ mask, uint32_t* __restrict__ pmL) {
    int tid = blockIdx.x * 256 + threadIdx.x;       // 0 .. 512*32*16-1
    int c  = tid & 15;
    int t  = (tid >> 4) & (NT - 1);
    int q4 = tid >> 9;
    uint32_t bits = 0;
    #pragma unroll
    for (int r = 0; r < 4; ++r)
        #pragma unroll
        for (int n = 0; n < 4; ++n) {
            int q = q4 * 4 + r;
            int k = t * KTI + n * 16 + c;
            if (mask[q * S_LEN + k]) bits |= 1u << (r * 4 + n);
        }
    pmL[tid] = bits;
}

// K (fp32 [bh][s][d]) -> bf16 same layout
__global__ void conv_k_kernel(const float* __restrict__ K, uint16_t* __restrict__ Kb) {
    size_t i = ((size_t)blockIdx.x * 256 + threadIdx.x) * 8;
    float4 a = *reinterpret_cast<const float4*>(K + i);
    float4 b = *reinterpret_cast<const float4*>(K + i + 4);
    short8v o;
    o[0] = f2bf(a.x); o[1] = f2bf(a.y); o[2] = f2bf(a.z); o[3] = f2bf(a.w);
    o[4] = f2bf(b.x); o[5] = f2bf(b.y); o[6] = f2bf(b.z); o[7] = f2bf(b.w);
    *reinterpret_cast<short8v*>(Kb + i) = o;
}

// V (fp32 [bh][s][d]) -> bf16 transposed [bh][d][s]
__global__ void trans_v_kernel(const float* __restrict__ V, uint16_t* __restrict__ Vt) {
    __shared__ short Ts[DH][72];          // 144B row stride: 16B-aligned
    int bh = blockIdx.x;
    int t  = blockIdx.y;
    const float* Vb = V + ((size_t)bh * S_LEN + t * KTI) * DH;
    int tid = threadIdx.x;
    #pragma unroll
    for (int i = 0; i < 4; ++i) {
        int lin = tid + i * 256;          // 0..1023 (float4 index)
        int row = lin >> 4;
        int c4  = (lin & 15) << 2;
        float4 v4 = *reinterpret_cast<const float4*>(Vb + row * DH + c4);
        Ts[c4 + 0][row] = f2bf(v4.x);
        Ts[c4 + 1][row] = f2bf(v4.y);
        Ts[c4 + 2][row] = f2bf(v4.z);
        Ts[c4 + 3][row] = f2bf(v4.w);
    }
    __syncthreads();
    #pragma unroll
    for (int i = 0; i < 2; ++i) {
        int lin = tid + i * 256;          // 0..511 (short8 index)
        int d   = lin >> 3;
        int k8  = (lin & 7) << 3;
        short8v o = *reinterpret_cast<const short8v*>(&Ts[d][k8]);
        *reinterpret_cast<short8v*>(Vt + ((size_t)bh * DH + d) * S_LEN + t * KTI + k8) = o;
    }
}

// ---------- main attention kernel ----------

__global__ __launch_bounds__(NTHR, 4)
void attn_kernel(const float* __restrict__ Q, const uint16_t* __restrict__ Kbf,
                 const uint16_t* __restrict__ VTb, const uint32_t* __restrict__ pmask,
                 float* __restrict__ outC, float* __restrict__ outA)
{
    __shared__ short Qs[QR][72];         // bf16 bits, padded stride
    __shared__ short Ks[2][KTI][72];     // double-buffered K tile
    __shared__ short VT[2][DH][72];      // double-buffered V^T tile
    __shared__ short Ps[8][16][72];      // per-wave P tile (A-frag layout)

    const int bh  = blockIdx.x;
    const int q0  = blockIdx.y * QR;
    const int tid = threadIdx.x;
    const int w   = tid >> 6;
    const int l   = tid & 63;
    const int l16 = l & 15;
    const int g   = l >> 4;
    const int srow = tid >> 3;           // staging row (0..63)
    const int scol = (tid & 7) << 3;     // staging col (0,8,...,56)

    const float*    Qb  = Q   + ((size_t)bh * S_LEN + q0) * DH;
    const uint16_t* Kbb = Kbf + (size_t)bh * S_LEN * DH;       // [s][d]
    const uint16_t* Vbb = VTb + (size_t)bh * DH * S_LEN;       // [d][s]
    float* Cb = outC + ((size_t)bh * S_LEN + q0) * DH;
    float* Ab = outA + (size_t)bh * S_LEN * S_LEN + (size_t)q0 * S_LEN;

    // ---- stage Q tile (128x64 fp32 -> bf16, once) ----
    #pragma unroll
    for (int i = 0; i < 4; ++i) {
        int v   = tid + i * NTHR;        // 0..2047 (float4 index)
        int row = v >> 4;
        int c4  = (v & 15) << 2;
        float4 q4 = *reinterpret_cast<const float4*>(Qb + row * DH + c4);
        short* dst = &Qs[row][c4];
        dst[0] = f2bf(q4.x); dst[1] = f2bf(q4.y); dst[2] = f2bf(q4.z); dst[3] = f2bf(q4.w);
    }
    __syncthreads();

    // per-wave Q A-fragments (rows w*16 + l16), two K=32 steps
    short8v aq0 = *reinterpret_cast<const short8v*>(&Qs[w * 16 + l16][g * 8]);
    short8v aq1 = *reinterpret_cast<const short8v*>(&Qs[w * 16 + l16][32 + g * 8]);

    const uint32_t* pmb = pmask + (size_t)((q0 >> 2) + (w << 2) + g) * (NT * 16) + l16;

    // ================= phase 1: softmax denominators (fixed-bias, no max) =================
    float ls[4] = {0.f, 0.f, 0.f, 0.f};
    {
        short8v kk = *reinterpret_cast<const short8v*>(Kbb + (size_t)srow * DH + scol);
        *reinterpret_cast<short8v*>(&Ks[0][srow][scol]) = kk;
    }
    __syncthreads();

    for (int t = 0; t < NT; ++t) {
        const int  cur  = t & 1;
        const bool more = (t + 1 < NT);
        short8v nk;
        if (more)
            nk = *reinterpret_cast<const short8v*>(Kbb + (size_t)((t + 1) * KTI + srow) * DH + scol);

        uint32_t mb = pmb[t << 4];

        f32x4 acc[4];
        #pragma unroll
        for (int n = 0; n < 4; ++n) {
            short8v b0 = *reinterpret_cast<const short8v*>(&Ks[cur][n * 16 + l16][g * 8]);
            short8v b1 = *reinterpret_cast<const short8v*>(&Ks[cur][n * 16 + l16][32 + g * 8]);
            f32x4 a = {0.f, 0.f, 0.f, 0.f};
            a = __builtin_amdgcn_mfma_f32_16x16x32_bf16(aq0, b0, a, 0, 0, 0);
            a = __builtin_amdgcn_mfma_f32_16x16x32_bf16(aq1, b1, a, 0, 0, 0);
            acc[n] = a;
        }

        #pragma unroll
        for (int n = 0; n < 4; ++n)
            #pragma unroll
            for (int r = 0; r < 4; ++r) {
                float e = __builtin_amdgcn_exp2f(acc[n][r] * SCALE2 - EXPB2);
                ls[r] += ((mb >> (r * 4 + n)) & 1u) ? e : 0.f;
            }

        if (more)
            *reinterpret_cast<short8v*>(&Ks[cur ^ 1][srow][scol]) = nk;
        __syncthreads();
    }

    // reduce row sums across the 16-lane group, once
    float li[4];
    #pragma unroll
    for (int r = 0; r < 4; ++r) {
        float v = ls[r];
        v += __shfl_xor(v, 1);
        v += __shfl_xor(v, 2);
        v += __shfl_xor(v, 4);
        v += __shfl_xor(v, 8);
        li[r] = 1.0f / v;
    }

    f32x4 acco[4];
    #pragma unroll
    for (int n = 0; n < 4; ++n) acco[n] = (f32x4){0.f, 0.f, 0.f, 0.f};

    // ================= phase 2: attn write + PV =================
    {
        short8v kk = *reinterpret_cast<const short8v*>(Kbb + (size_t)srow * DH + scol);
        *reinterpret_cast<short8v*>(&Ks[0][srow][scol]) = kk;
        short8v vv = *reinterpret_cast<const short8v*>(Vbb + (size_t)srow * S_LEN + scol);
        *reinterpret_cast<short8v*>(&VT[0][srow][scol]) = vv;
    }
    __syncthreads();

    for (int t = 0; t < NT; ++t) {
        const int  cur  = t & 1;
        const bool more = (t + 1 < NT);
        short8v nk, nv;
        if (more) {
            nk = *reinterpret_cast<const short8v*>(Kbb + (size_t)((t + 1) * KTI + srow) * DH + scol);
            nv = *reinterpret_cast<const short8v*>(Vbb + (size_t)srow * S_LEN + (t + 1) * KTI + scol);
        }
        uint32_t mb = pmb[t << 4];

        f32x4 acc[4];
        #pragma unroll
        for (int n = 0; n < 4; ++n) {
            short8v b0 = *reinterpret_cast<const short8v*>(&Ks[cur][n * 16 + l16][g * 8]);
            short8v b1 = *reinterpret_cast<const short8v*>(&Ks[cur][n * 16 + l16][32 + g * 8]);
            f32x4 a = {0.f, 0.f, 0.f, 0.f};
            a = __builtin_amdgcn_mfma_f32_16x16x32_bf16(aq0, b0, a, 0, 0, 0);
            a = __builtin_amdgcn_mfma_f32_16x16x32_bf16(aq1, b1, a, 0, 0, 0);
            acc[n] = a;
        }

        // normalized probabilities -> Ps (bf16, A-frag layout)
        #pragma unroll
        for (int n = 0; n < 4; ++n)
            #pragma unroll
            for (int r = 0; r < 4; ++r) {
                float e = __builtin_amdgcn_exp2f(acc[n][r] * SCALE2 - EXPB2) * li[r];
                float p = ((mb >> (r * 4 + n)) & 1u) ? e : 0.0f;
                Ps[w][4 * g + r][n * 16 + l16] = f2bf(p);
            }

        // order the Ps short-writes before the vector readback (TBAA-proof)
        asm volatile("" ::: "memory");

        // attn store: read Ps back (short4v aliases short), write full 256B
        // row-chunks as float4: instr j covers rows 4j..4j+3 completely
        {
            float* Aw = Ab + (size_t)(w * 16) * S_LEN + t * KTI;
            #pragma unroll
            for (int j = 0; j < 4; ++j) {
                int r4 = 4 * j + (l >> 4);
                short4v pv4 = *reinterpret_cast<const short4v*>(&Ps[w][r4][(l & 15) * 4]);
                float4 o;
                o.x = __builtin_bit_cast(float, ((uint32_t)(uint16_t)pv4[0]) << 16);
                o.y = __builtin_bit_cast(float, ((uint32_t)(uint16_t)pv4[1]) << 16);
                o.z = __builtin_bit_cast(float, ((uint32_t)(uint16_t)pv4[2]) << 16);
                o.w = __builtin_bit_cast(float, ((uint32_t)(uint16_t)pv4[3]) << 16);
                *reinterpret_cast<float4*>(Aw + (size_t)r4 * S_LEN + (l & 15) * 4) = o;
            }
        }

        // PV: O += P(16xKTI) * V(KTIxDH)
        short8v ap0 = *reinterpret_cast<const short8v*>(&Ps[w][l16][g * 8]);
        short8v ap1 = *reinterpret_cast<const short8v*>(&Ps[w][l16][32 + g * 8]);
        #pragma unroll
        for (int n = 0; n < 4; ++n) {
            short8v b0 = *reinterpret_cast<const short8v*>(&VT[cur][n * 16 + l16][g * 8]);
            short8v b1 = *reinterpret_cast<const short8v*>(&VT[cur][n * 16 + l16][32 + g * 8]);
            acco[n] = __builtin_amdgcn_mfma_f32_16x16x32_bf16(ap0, b0, acco[n], 0, 0, 0);
            acco[n] = __builtin_amdgcn_mfma_f32_16x16x32_bf16(ap1, b1, acco[n], 0, 0, 0);
        }

        if (more) {
            const int nb = cur ^ 1;
            *reinterpret_cast<short8v*>(&Ks[nb][srow][scol]) = nk;
            *reinterpret_cast<short8v*>(&VT[nb][srow][scol]) = nv;
        }
        __syncthreads();
    }

    // ---- write context ----
    #pragma unroll
    for (int n = 0; n < 4; ++n)
        #pragma unroll
        for (int r = 0; r < 4; ++r)
            Cb[(w * 16 + 4 * g + r) * DH + n * 16 + l16] = acco[n][r];
}

extern "C" void kernel_launch(void* const* d_in, const int* in_sizes, int n_in,
                              void* d_out, int out_size, void* d_ws, size_t ws_size,
                              hipStream_t stream)
{
    const float* Q    = (const float*)d_in[0];
    const float* K    = (const float*)d_in[1];
    const float* V    = (const float*)d_in[2];
    const int*   mask = (const int*)d_in[3];

    float* outC = (float*)d_out;
    float* outA = (float*)d_out + (size_t)NBH * S_LEN * DH;   // context first, then attn

    char* ws = (char*)d_ws;
    uint32_t* pmL = (uint32_t*)ws;                             // 1 MB packed mask
    uint16_t* Kbf = (uint16_t*)(ws + (1 << 20));               // 16 MB bf16 K
    uint16_t* VTb = (uint16_t*)(ws + (17 << 20));              // 16 MB bf16 V^T

    pack_mask_kernel<<<dim3((S_LEN / 4) * NT * 16 / 256), 256, 0, stream>>>(mask, pmL);
    conv_k_kernel<<<dim3((NBH * S_LEN * DH) / (256 * 8)), 256, 0, stream>>>(K, Kbf);
    trans_v_kernel<<<dim3(NBH, NT), 256, 0, stream>>>(V, VTb);
    attn_kernel<<<dim3(NBH, S_LEN / QR), NTHR, 0, stream>>>(Q, Kbf, VTb, pmL, outC, outA);
}